// Round 1
// baseline (193.996 us; speedup 1.0000x reference)
//
#include <hip/hip_runtime.h>
#include <hip/hip_bf16.h>

#define N_ROWS 8192
#define DIM 256
#define NANCH 64
#define NVIEW 128
#define BM 32

typedef __attribute__((ext_vector_type(8))) short bf16x8;
typedef __attribute__((ext_vector_type(4))) float f32x4;
typedef __attribute__((ext_vector_type(4))) float float4v;
typedef __attribute__((ext_vector_type(4))) unsigned short ushort4v;

__device__ __forceinline__ unsigned short f2bf(float x) {
  union { float f; unsigned int u; } c; c.f = x;
  unsigned int u = c.u;
  unsigned int r = (u + 0x7fffu + ((u >> 16) & 1u)) >> 16;
  return (unsigned short)r;
}

// fp32 -> bf16 with 1/sqrt(TEMPERATURE) prescale so MFMA output == logits
__global__ void cast_scale_kernel(const float4v* __restrict__ in,
                                  ushort4v* __restrict__ out, int n4) {
  int i = blockIdx.x * blockDim.x + threadIdx.x;
  if (i < n4) {
    const float s = 3.16227766016838f; // 1/sqrt(0.1)
    float4v v = in[i];
    ushort4v o;
    o.x = f2bf(v.x * s);
    o.y = f2bf(v.y * s);
    o.z = f2bf(v.z * s);
    o.w = f2bf(v.w * s);
    out[i] = o;
  }
}

__global__ __launch_bounds__(256) void pcl_main(const unsigned short* __restrict__ Xb,
                                                const int* __restrict__ labels,
                                                float* __restrict__ partials) {
  const int blk = blockIdx.x;          // 0..255
  const int r0 = blk * BM;             // global row start (32 rows per block)
  const int tid = threadIdx.x;
  const int wid = tid >> 6;            // wave 0..3 -> column sub-tile
  const int lane = tid & 63;
  const int lo = lane & 15;
  const int hi = lane >> 4;

  __shared__ int slab[NANCH];
  __shared__ float sredA[4][BM];
  __shared__ float sredB[4][BM];

  if (tid < NANCH) slab[tid] = labels[tid];
  __syncthreads();
  const int La = slab[r0 >> 7];

  // Hoist A fragments (this block's 32 rows, all K=256) into registers.
  // Operand layout: lane holds 8 contiguous k at k-offset (lane>>4)*8, row = lane&15.
  bf16x8 afrag[2][8];
#pragma unroll
  for (int ri = 0; ri < 2; ++ri) {
#pragma unroll
    for (int ks = 0; ks < 8; ++ks) {
      const unsigned short* p = Xb + (r0 + ri * 16 + lo) * DIM + ks * 32 + hi * 8;
      afrag[ri][ks] = *(const bf16x8*)p;
    }
  }

  // Per-lane online state: 8 row-slots (ri*4+reg), each over this lane's column slice.
  float m[8], ns[8];
#pragma unroll
  for (int t = 0; t < 8; ++t) { m[t] = -1e30f; ns[t] = 0.f; }

  // ---------------- Pass 1: row max + negative-exp sum ----------------
  for (int b = 0; b < NANCH; ++b) {
    const bool isneg = (slab[b] != La);
    const int c0 = b * NVIEW + wid * 32;
    f32x4 acc[2][2];
#pragma unroll
    for (int ri = 0; ri < 2; ++ri)
#pragma unroll
      for (int ci = 0; ci < 2; ++ci)
        acc[ri][ci] = (f32x4){0.f, 0.f, 0.f, 0.f};

#pragma unroll
    for (int ks = 0; ks < 8; ++ks) {
      bf16x8 b0 = *(const bf16x8*)(Xb + (c0 + lo) * DIM + ks * 32 + hi * 8);
      bf16x8 b1 = *(const bf16x8*)(Xb + (c0 + 16 + lo) * DIM + ks * 32 + hi * 8);
      acc[0][0] = __builtin_amdgcn_mfma_f32_16x16x32_bf16(afrag[0][ks], b0, acc[0][0], 0, 0, 0);
      acc[0][1] = __builtin_amdgcn_mfma_f32_16x16x32_bf16(afrag[0][ks], b1, acc[0][1], 0, 0, 0);
      acc[1][0] = __builtin_amdgcn_mfma_f32_16x16x32_bf16(afrag[1][ks], b0, acc[1][0], 0, 0, 0);
      acc[1][1] = __builtin_amdgcn_mfma_f32_16x16x32_bf16(afrag[1][ks], b1, acc[1][1], 0, 0, 0);
    }

#pragma unroll
    for (int ri = 0; ri < 2; ++ri) {
#pragma unroll
      for (int reg = 0; reg < 4; ++reg) {
        const int t = ri * 4 + reg;
        float v0 = acc[ri][0][reg];
        float v1 = acc[ri][1][reg];
        float tm = fmaxf(v0, v1);
        // fast-path: whole contribution underflows (exp(<-40) ~ 0)
        if (tm > m[t] - 40.f) {
          float mn = fmaxf(m[t], tm);
          float scale = __expf(m[t] - mn);
          float add = isneg ? (__expf(v0 - mn) + __expf(v1 - mn)) : 0.f;
          ns[t] = ns[t] * scale + add;
          m[t] = mn;
        }
      }
    }
  }

  // Combine (m, ns) across the 16-lane column groups.
#pragma unroll
  for (int t = 0; t < 8; ++t) {
#pragma unroll
    for (int st = 1; st < 16; st <<= 1) {
      float mo = __shfl_xor(m[t], st);
      float no = __shfl_xor(ns[t], st);
      float mn = fmaxf(m[t], mo);
      ns[t] = ns[t] * __expf(m[t] - mn) + no * __expf(mo - mn);
      m[t] = mn;
    }
  }

  // Combine across the 4 waves via LDS.
  if (lo == 0) {
#pragma unroll
    for (int ri = 0; ri < 2; ++ri)
#pragma unroll
      for (int reg = 0; reg < 4; ++reg) {
        int row = ri * 16 + hi * 4 + reg;
        sredA[wid][row] = m[ri * 4 + reg];
        sredB[wid][row] = ns[ri * 4 + reg];
      }
  }
  __syncthreads();

  float mf[8], nsf[8];
#pragma unroll
  for (int ri = 0; ri < 2; ++ri) {
#pragma unroll
    for (int reg = 0; reg < 4; ++reg) {
      int row = ri * 16 + hi * 4 + reg;
      float m0 = sredA[0][row], m1 = sredA[1][row], m2 = sredA[2][row], m3 = sredA[3][row];
      float M = fmaxf(fmaxf(m0, m1), fmaxf(m2, m3));
      float NS = sredB[0][row] * __expf(m0 - M) + sredB[1][row] * __expf(m1 - M) +
                 sredB[2][row] * __expf(m2 - M) + sredB[3][row] * __expf(m3 - M);
      mf[ri * 4 + reg] = M;
      nsf[ri * 4 + reg] = NS;
    }
  }

  // ---------------- Pass 2: positives only (same-label anchors) ----------------
  float pos[8];
#pragma unroll
  for (int t = 0; t < 8; ++t) pos[t] = 0.f;

  for (int b = 0; b < NANCH; ++b) {
    if (slab[b] != La) continue;
    const int c0 = b * NVIEW + wid * 32;
    f32x4 acc[2][2];
#pragma unroll
    for (int ri = 0; ri < 2; ++ri)
#pragma unroll
      for (int ci = 0; ci < 2; ++ci)
        acc[ri][ci] = (f32x4){0.f, 0.f, 0.f, 0.f};

#pragma unroll
    for (int ks = 0; ks < 8; ++ks) {
      bf16x8 b0 = *(const bf16x8*)(Xb + (c0 + lo) * DIM + ks * 32 + hi * 8);
      bf16x8 b1 = *(const bf16x8*)(Xb + (c0 + 16 + lo) * DIM + ks * 32 + hi * 8);
      acc[0][0] = __builtin_amdgcn_mfma_f32_16x16x32_bf16(afrag[0][ks], b0, acc[0][0], 0, 0, 0);
      acc[0][1] = __builtin_amdgcn_mfma_f32_16x16x32_bf16(afrag[0][ks], b1, acc[0][1], 0, 0, 0);
      acc[1][0] = __builtin_amdgcn_mfma_f32_16x16x32_bf16(afrag[1][ks], b0, acc[1][0], 0, 0, 0);
      acc[1][1] = __builtin_amdgcn_mfma_f32_16x16x32_bf16(afrag[1][ks], b1, acc[1][1], 0, 0, 0);
    }

#pragma unroll
    for (int ri = 0; ri < 2; ++ri) {
#pragma unroll
      for (int ci = 0; ci < 2; ++ci) {
#pragma unroll
        for (int reg = 0; reg < 4; ++reg) {
          const int t = ri * 4 + reg;
          int grow = r0 + ri * 16 + hi * 4 + reg;
          int gcol = c0 + ci * 16 + lo;
          if (grow != gcol) {  // exclude diagonal
            float d = acc[ri][ci][reg] - mf[t];
            pos[t] += d - __logf(__expf(d) + nsf[t] + 1e-10f);
          }
        }
      }
    }
  }

  // Sum pos across 16-lane groups.
#pragma unroll
  for (int t = 0; t < 8; ++t) {
#pragma unroll
    for (int st = 1; st < 16; st <<= 1) pos[t] += __shfl_xor(pos[t], st);
  }

  __syncthreads();  // protect sredA reuse
  if (lo == 0) {
#pragma unroll
    for (int ri = 0; ri < 2; ++ri)
#pragma unroll
      for (int reg = 0; reg < 4; ++reg) {
        int row = ri * 16 + hi * 4 + reg;
        sredA[wid][row] = pos[ri * 4 + reg];
      }
  }
  __syncthreads();

  // positive count (uniform per block): 128 * cnt[label] - 1
  int cnt = 0;
  for (int b = 0; b < NANCH; ++b) cnt += (slab[b] == La) ? 1 : 0;
  const float poscnt = (float)(cnt * NVIEW - 1);

  if (tid < BM) {
    float P = sredA[0][tid] + sredA[1][tid] + sredA[2][tid] + sredA[3][tid];
    sredB[0][tid] = P / poscnt;
  }
  __syncthreads();
  if (tid == 0) {
    float s = 0.f;
    for (int r = 0; r < BM; ++r) s += sredB[0][r];
    partials[blk] = s;
  }
}

__global__ void final_reduce(const float* __restrict__ partials, float* __restrict__ out) {
  __shared__ float s[256];
  int t = threadIdx.x;
  s[t] = partials[t];
  __syncthreads();
  for (int st = 128; st > 0; st >>= 1) {
    if (t < st) s[t] += s[t + st];
    __syncthreads();
  }
  if (t == 0) {
    // loss = mean over N rows of -(T/BASE_T) * mean_log_prob_pos
    out[0] = -(0.1f / 0.07f) * s[0] / (float)N_ROWS;
  }
}

extern "C" void kernel_launch(void* const* d_in, const int* in_sizes, int n_in,
                              void* d_out, int out_size, void* d_ws, size_t ws_size,
                              hipStream_t stream) {
  const float* feats = (const float*)d_in[0];
  const int* labels = (const int*)d_in[1];
  float* out = (float*)d_out;

  unsigned short* Xb = (unsigned short*)d_ws;
  float* partials = (float*)((char*)d_ws + (size_t)N_ROWS * DIM * sizeof(unsigned short));

  const int n4 = N_ROWS * DIM / 4;
  cast_scale_kernel<<<(n4 + 255) / 256, 256, 0, stream>>>((const float4v*)feats,
                                                          (ushort4v*)Xb, n4);
  pcl_main<<<N_ROWS / BM, 256, 0, stream>>>(Xb, labels, partials);
  final_reduce<<<1, 256, 0, stream>>>(partials, out);
}

// Round 2
// 153.398 us; speedup vs baseline: 1.2647x; 1.2647x over previous
//
#include <hip/hip_runtime.h>
#include <hip/hip_bf16.h>

#define N_ROWS 8192
#define DIM 256
#define NANCH 64
#define NVIEW 128
#define BM 32
#define NWAVE 16

typedef __attribute__((ext_vector_type(8))) short bf16x8;
typedef __attribute__((ext_vector_type(4))) float f32x4;
typedef __attribute__((ext_vector_type(4))) float float4v;
typedef __attribute__((ext_vector_type(4))) unsigned short ushort4v;

__device__ __forceinline__ unsigned short f2bf(float x) {
  union { float f; unsigned int u; } c; c.f = x;
  unsigned int u = c.u;
  unsigned int r = (u + 0x7fffu + ((u >> 16) & 1u)) >> 16;
  return (unsigned short)r;
}

// fp32 -> bf16 with 1/sqrt(TEMPERATURE) prescale so MFMA output == logits
__global__ void cast_scale_kernel(const float4v* __restrict__ in,
                                  ushort4v* __restrict__ out, int n4) {
  int i = blockIdx.x * blockDim.x + threadIdx.x;
  if (i < n4) {
    const float s = 3.16227766016838f; // 1/sqrt(0.1)
    float4v v = in[i];
    ushort4v o;
    o.x = f2bf(v.x * s);
    o.y = f2bf(v.y * s);
    o.z = f2bf(v.z * s);
    o.w = f2bf(v.w * s);
    out[i] = o;
  }
}

// 1024-thread blocks (16 waves). Wave w: column-subtile (w&3)*32 within each
// anchor, anchor subset b % 4 == (w>>2). 4 waves/SIMD for latency hiding.
__global__ __launch_bounds__(1024) void pcl_main(const unsigned short* __restrict__ Xb,
                                                 const int* __restrict__ labels,
                                                 float* __restrict__ partials) {
  const int blk = blockIdx.x;          // 0..255
  const int r0 = blk * BM;             // global row start (32 rows per block)
  const int tid = threadIdx.x;
  const int wid = tid >> 6;            // 0..15
  const int lane = tid & 63;
  const int lo = lane & 15;
  const int hi = lane >> 4;
  const int cq = wid & 3;              // column quarter (32 cols)
  const int bq = wid >> 2;             // anchor phase 0..3

  __shared__ int slab[NANCH];
  __shared__ float sm[NWAVE][BM];
  __shared__ float sns[NWAVE][BM];
  __shared__ float smf[BM];
  __shared__ float snsf[BM];
  __shared__ int poslist[NANCH];
  __shared__ int scnt;

  if (tid < NANCH) slab[tid] = labels[tid];
  __syncthreads();
  const int La = slab[r0 >> 7];

  // Hoist A fragments (this block's 32 rows, all K=256) into registers.
  // Lane holds 8 contiguous k at k-offset (lane>>4)*8, row = lane&15.
  bf16x8 afrag[2][8];
#pragma unroll
  for (int ri = 0; ri < 2; ++ri) {
#pragma unroll
    for (int ks = 0; ks < 8; ++ks) {
      const unsigned short* p = Xb + (r0 + ri * 16 + lo) * DIM + ks * 32 + hi * 8;
      afrag[ri][ks] = *(const bf16x8*)p;
    }
  }

  // Per-lane online state: 8 row-slots (ri*4+reg) over this lane's column slice.
  float m[8], ns[8];
#pragma unroll
  for (int t = 0; t < 8; ++t) { m[t] = -1e30f; ns[t] = 0.f; }

  // ---------------- Pass 1: row max + negative-exp sum ----------------
  for (int j = 0; j < NANCH / 4; ++j) {
    const int b = bq + 4 * j;
    const bool isneg = (slab[b] != La);
    const int c0 = b * NVIEW + cq * 32;
    f32x4 acc[2][2];
#pragma unroll
    for (int ri = 0; ri < 2; ++ri)
#pragma unroll
      for (int ci = 0; ci < 2; ++ci)
        acc[ri][ci] = (f32x4){0.f, 0.f, 0.f, 0.f};

#pragma unroll
    for (int ks = 0; ks < 8; ++ks) {
      bf16x8 b0 = *(const bf16x8*)(Xb + (c0 + lo) * DIM + ks * 32 + hi * 8);
      bf16x8 b1 = *(const bf16x8*)(Xb + (c0 + 16 + lo) * DIM + ks * 32 + hi * 8);
      acc[0][0] = __builtin_amdgcn_mfma_f32_16x16x32_bf16(afrag[0][ks], b0, acc[0][0], 0, 0, 0);
      acc[0][1] = __builtin_amdgcn_mfma_f32_16x16x32_bf16(afrag[0][ks], b1, acc[0][1], 0, 0, 0);
      acc[1][0] = __builtin_amdgcn_mfma_f32_16x16x32_bf16(afrag[1][ks], b0, acc[1][0], 0, 0, 0);
      acc[1][1] = __builtin_amdgcn_mfma_f32_16x16x32_bf16(afrag[1][ks], b1, acc[1][1], 0, 0, 0);
    }

#pragma unroll
    for (int ri = 0; ri < 2; ++ri) {
#pragma unroll
      for (int reg = 0; reg < 4; ++reg) {
        const int t = ri * 4 + reg;
        float v0 = acc[ri][0][reg];
        float v1 = acc[ri][1][reg];
        float tm = fmaxf(v0, v1);
        // fast-path: whole contribution underflows (exp(<-40) ~ 0)
        if (tm > m[t] - 40.f) {
          float mn = fmaxf(m[t], tm);
          float scale = __expf(m[t] - mn);
          float add = isneg ? (__expf(v0 - mn) + __expf(v1 - mn)) : 0.f;
          ns[t] = ns[t] * scale + add;
          m[t] = mn;
        }
      }
    }
  }

  // Combine (m, ns) across the 16-lane column groups within the wave.
#pragma unroll
  for (int t = 0; t < 8; ++t) {
#pragma unroll
    for (int st = 1; st < 16; st <<= 1) {
      float mo = __shfl_xor(m[t], st);
      float no = __shfl_xor(ns[t], st);
      float mn = fmaxf(m[t], mo);
      ns[t] = ns[t] * __expf(m[t] - mn) + no * __expf(mo - mn);
      m[t] = mn;
    }
  }

  // Stash per-wave (m, ns) in LDS.
  if (lo == 0) {
#pragma unroll
    for (int ri = 0; ri < 2; ++ri)
#pragma unroll
      for (int reg = 0; reg < 4; ++reg) {
        int row = ri * 16 + hi * 4 + reg;
        sm[wid][row] = m[ri * 4 + reg];
        sns[wid][row] = ns[ri * 4 + reg];
      }
  }
  // Build positive-anchor list concurrently.
  if (tid == 0) {
    int c = 0;
    for (int b = 0; b < NANCH; ++b)
      if (slab[b] == La) poslist[c++] = b;
    scnt = c;
  }
  __syncthreads();

  // Merge across 16 waves -> final per-row (max, negsum) in LDS.
  if (tid < BM) {
    float M = -1e30f;
#pragma unroll
    for (int w = 0; w < NWAVE; ++w) M = fmaxf(M, sm[w][tid]);
    float NS = 0.f;
#pragma unroll
    for (int w = 0; w < NWAVE; ++w) NS += sns[w][tid] * __expf(sm[w][tid] - M);
    smf[tid] = M;
    snsf[tid] = NS;
  }
  __syncthreads();
  const int cnt = scnt;

  // ---------------- Pass 2: positives only ----------------
  float pos[8];
#pragma unroll
  for (int t = 0; t < 8; ++t) pos[t] = 0.f;

  for (int p = bq; p < cnt; p += 4) {
    const int b = poslist[p];
    const int c0 = b * NVIEW + cq * 32;
    f32x4 acc[2][2];
#pragma unroll
    for (int ri = 0; ri < 2; ++ri)
#pragma unroll
      for (int ci = 0; ci < 2; ++ci)
        acc[ri][ci] = (f32x4){0.f, 0.f, 0.f, 0.f};

#pragma unroll
    for (int ks = 0; ks < 8; ++ks) {
      bf16x8 b0 = *(const bf16x8*)(Xb + (c0 + lo) * DIM + ks * 32 + hi * 8);
      bf16x8 b1 = *(const bf16x8*)(Xb + (c0 + 16 + lo) * DIM + ks * 32 + hi * 8);
      acc[0][0] = __builtin_amdgcn_mfma_f32_16x16x32_bf16(afrag[0][ks], b0, acc[0][0], 0, 0, 0);
      acc[0][1] = __builtin_amdgcn_mfma_f32_16x16x32_bf16(afrag[0][ks], b1, acc[0][1], 0, 0, 0);
      acc[1][0] = __builtin_amdgcn_mfma_f32_16x16x32_bf16(afrag[1][ks], b0, acc[1][0], 0, 0, 0);
      acc[1][1] = __builtin_amdgcn_mfma_f32_16x16x32_bf16(afrag[1][ks], b1, acc[1][1], 0, 0, 0);
    }

#pragma unroll
    for (int ri = 0; ri < 2; ++ri) {
#pragma unroll
      for (int ci = 0; ci < 2; ++ci) {
#pragma unroll
        for (int reg = 0; reg < 4; ++reg) {
          const int t = ri * 4 + reg;
          const int row = ri * 16 + hi * 4 + reg;
          int grow = r0 + row;
          int gcol = c0 + ci * 16 + lo;
          if (grow != gcol) {  // exclude diagonal
            float d = acc[ri][ci][reg] - smf[row];
            pos[t] += d - __logf(__expf(d) + snsf[row] + 1e-10f);
          }
        }
      }
    }
  }

  // Sum pos across 16-lane groups.
#pragma unroll
  for (int t = 0; t < 8; ++t) {
#pragma unroll
    for (int st = 1; st < 16; st <<= 1) pos[t] += __shfl_xor(pos[t], st);
  }

  __syncthreads();  // protect sm reuse
  if (lo == 0) {
#pragma unroll
    for (int ri = 0; ri < 2; ++ri)
#pragma unroll
      for (int reg = 0; reg < 4; ++reg) {
        int row = ri * 16 + hi * 4 + reg;
        sm[wid][row] = pos[ri * 4 + reg];
      }
  }
  __syncthreads();

  // positive count per row (uniform per block): 128 * cnt - 1
  const float poscnt = (float)(cnt * NVIEW - 1);

  if (tid < BM) {
    float P = 0.f;
#pragma unroll
    for (int w = 0; w < NWAVE; ++w) P += sm[w][tid];
    smf[tid] = P / poscnt;
  }
  __syncthreads();
  if (tid == 0) {
    float s = 0.f;
    for (int r = 0; r < BM; ++r) s += smf[r];
    partials[blk] = s;
  }
}

__global__ void final_reduce(const float* __restrict__ partials, float* __restrict__ out) {
  __shared__ float s[256];
  int t = threadIdx.x;
  s[t] = partials[t];
  __syncthreads();
  for (int st = 128; st > 0; st >>= 1) {
    if (t < st) s[t] += s[t + st];
    __syncthreads();
  }
  if (t == 0) {
    // loss = mean over N rows of -(T/BASE_T) * mean_log_prob_pos
    out[0] = -(0.1f / 0.07f) * s[0] / (float)N_ROWS;
  }
}

extern "C" void kernel_launch(void* const* d_in, const int* in_sizes, int n_in,
                              void* d_out, int out_size, void* d_ws, size_t ws_size,
                              hipStream_t stream) {
  const float* feats = (const float*)d_in[0];
  const int* labels = (const int*)d_in[1];
  float* out = (float*)d_out;

  unsigned short* Xb = (unsigned short*)d_ws;
  float* partials = (float*)((char*)d_ws + (size_t)N_ROWS * DIM * sizeof(unsigned short));

  const int n4 = N_ROWS * DIM / 4;
  cast_scale_kernel<<<(n4 + 255) / 256, 256, 0, stream>>>((const float4v*)feats,
                                                          (ushort4v*)Xb, n4);
  pcl_main<<<N_ROWS / BM, 1024, 0, stream>>>(Xb, labels, partials);
  final_reduce<<<1, 256, 0, stream>>>(partials, out);
}